// Round 5
// baseline (3303.017 us; speedup 1.0000x reference)
//
#include <hip/hip_runtime.h>

// GRU decoder, bf16 MFMA, 16 waves/block.
// R5: THE spill fix. Empirically this toolchain treats __launch_bounds__'s
// 2nd arg CUDA-style (min BLOCKS per CU): (512,2)->128 VGPR, (1024,4)->64,
// (1024,2)->64. Demand ~115 regs -> every prior MFMA round spilled to
// scratch (R4: 1.7 GB WRITE, 7.7 GB FETCH of spill traffic). (1024,1)
// gives a 128-reg cap >= demand. Everything else identical to R4.
//
// Block owns BM=32 rows for all T=96 steps. Wave w owns h-cols [w*16,w*16+16)
// across all 3 gates. Wk (K=64) resident in registers; prev_out rank-1 term
// in fp32 epilogue. Wr streamed from L2 (swizzled B-fragments, 16B/lane).
// h carried fp32 in registers; bf16 copy in LDS for next step's A-frags.

#define Bdim 8192
#define Tdim 96
#define Fdim 64
#define Hdim 256
#define BM   32
#define XS   72    // feat row stride (bf16): 64 + 8 pad
#define HS   264   // h row stride (bf16): 256 + 8 pad
#define OS   97    // outbuf row stride (floats)

typedef __attribute__((ext_vector_type(8))) short s16x8;
typedef __attribute__((ext_vector_type(4))) float f32x4;

#define MFMA __builtin_amdgcn_mfma_f32_16x16x32_bf16

__device__ __forceinline__ unsigned short f2bf(float f) {
    union { float f; unsigned u; } v; v.f = f;
    unsigned r = v.u + 0x7FFFu + ((v.u >> 16) & 1u);   // RNE
    return (unsigned short)(r >> 16);
}

// ---- one-time weight conversion + B-fragment swizzle ----
// frag f, lane l: 8 bf16 at [f*512 + l*8]; lane holds
// B[k = kt*32 + (l>>4)*8 + j][n = g*256 + w*16 + (l&15)]
// sR: f = (w*8 + kt)*3 + g   (w 0..15, kt 0..7, g 0..2)  -> 384 frags
// sK: f = (w*2 + kt)*3 + g   (kt 0..1), source rows Wk[1+k] -> 96 frags
__global__ void prep_swz(const float* __restrict__ Wk, const float* __restrict__ Wr,
                         unsigned short* __restrict__ sK, unsigned short* __restrict__ sR) {
    int idx = blockIdx.x * blockDim.x + threadIdx.x;
    int lane = idx & 63;
    int q = lane >> 4, cc = lane & 15;
    if (idx < 24576) {                       // sR
        int f = idx >> 6;
        int g = f % 3; int rest = f / 3;
        int kt = rest & 7; int w = rest >> 3;
        int n = g * 256 + w * 16 + cc;
        unsigned short* d = sR + (size_t)idx * 8;
#pragma unroll
        for (int j = 0; j < 8; ++j)
            d[j] = f2bf(Wr[(size_t)(kt * 32 + q * 8 + j) * 768 + n]);
    } else if (idx < 24576 + 6144) {         // sK
        int i2 = idx - 24576;
        int f = i2 >> 6;
        int g = f % 3; int rest = f / 3;
        int kt = rest & 1; int w = rest >> 1;
        int n = g * 256 + w * 16 + cc;
        unsigned short* d = sK + (size_t)i2 * 8;
#pragma unroll
        for (int j = 0; j < 8; ++j)
            d[j] = f2bf(Wk[(size_t)(1 + kt * 32 + q * 8 + j) * 768 + n]);
    }
}

__launch_bounds__(1024, 1)
__global__ void gru_mfma4(
    const float* __restrict__ feat,       // [B,T,F]
    const float* __restrict__ init_state, // [B,H]
    const float* __restrict__ init_inp,   // [B,1]
    const unsigned short* __restrict__ sK,
    const unsigned short* __restrict__ sR,
    const float* __restrict__ Wk,         // row 0 (prev_out rank-1 term)
    const float* __restrict__ ib, const float* __restrict__ rb,
    const float* __restrict__ dw, const float* __restrict__ db,
    float* __restrict__ out)              // [B,T,1]
{
    __shared__ __align__(16) unsigned short xs[BM * XS];  // feat tile, bf16
    __shared__ __align__(16) unsigned short hs[BM * HS];  // h state, bf16
    __shared__ float wpart[2][16][BM];                    // dbl-buffered by t&1
    __shared__ float outbuf[BM * OS];

    const int tid  = threadIdx.x;
    const int lane = tid & 63;
    const int w    = tid >> 6;     // wave 0..15: h-cols [w*16, w*16+16)
    const int q    = lane >> 4;
    const int c    = lane & 15;
    const int b0   = blockIdx.x * BM;

    const int colh = w * 16 + c;
    const float bz   = ib[colh]       + rb[colh];
    const float brr  = ib[256 + colh] + rb[256 + colh];
    const float bxh  = ib[512 + colh];
    const float bhh  = rb[512 + colh];
    const float wk0z = Wk[colh], wk0r = Wk[256 + colh], wk0h = Wk[512 + colh];
    const float dwv  = dw[colh];
    const float dbv  = db[0];

    // init h: fp32 in regs + bf16 in LDS
    float hreg[2][4];
    float prevreg[2][4];
#pragma unroll
    for (int mt = 0; mt < 2; ++mt)
#pragma unroll
        for (int i = 0; i < 4; ++i) {
            int row = mt * 16 + q * 4 + i;
            float v = init_state[(size_t)(b0 + row) * Hdim + colh];
            hreg[mt][i] = v;
            hs[row * HS + colh] = f2bf(v);
            prevreg[mt][i] = init_inp[b0 + row];
        }

    // stage feat t=0 (512 threads: 32 rows x 16 float4)
    if (tid < 512) {
        int r = tid >> 4, fi = tid & 15;
        float4 f = *(const float4*)&feat[((size_t)(b0 + r) * Tdim + 0) * Fdim + fi * 4];
        ushort4 p; p.x = f2bf(f.x); p.y = f2bf(f.y); p.z = f2bf(f.z); p.w = f2bf(f.w);
        *(ushort4*)&xs[r * XS + fi * 4] = p;
    }

    // Wk fragments resident (2 kt x 3 g = 6 frags = 24 VGPR)
    s16x8 wkr[2][3];
    {
        const unsigned short* kp = sK + (size_t)(w * 6) * 512 + lane * 8;
#pragma unroll
        for (int kt = 0; kt < 2; ++kt)
#pragma unroll
            for (int g = 0; g < 3; ++g)
                wkr[kt][g] = *(const s16x8*)(kp + (kt * 3 + g) * 512);
    }
    const unsigned short* wrp = sR + (size_t)(w * 24) * 512 + lane * 8;

    __syncthreads();

    for (int t = 0; t < Tdim; ++t) {
        // ---- GEMMs (no dependence on prev_out) ----
        f32x4 az[2], arr[2], axh[2], ahh[2];
#pragma unroll
        for (int mt = 0; mt < 2; ++mt) {
            az[mt] = (f32x4)0.0f; arr[mt] = (f32x4)0.0f;
            axh[mt] = (f32x4)0.0f; ahh[mt] = (f32x4)0.0f;
        }

#pragma unroll
        for (int kt = 0; kt < 8; ++kt) {     // h GEMM, K=256, weights from L2
            s16x8 bzf = *(const s16x8*)(wrp + (size_t)(kt * 3 + 0) * 512);
            s16x8 brf = *(const s16x8*)(wrp + (size_t)(kt * 3 + 1) * 512);
            s16x8 bhf = *(const s16x8*)(wrp + (size_t)(kt * 3 + 2) * 512);
            s16x8 a0 = *(const s16x8*)&hs[c * HS + kt * 32 + q * 8];
            s16x8 a1 = *(const s16x8*)&hs[(16 + c) * HS + kt * 32 + q * 8];
            az[0]  = MFMA(a0, bzf, az[0], 0, 0, 0);
            az[1]  = MFMA(a1, bzf, az[1], 0, 0, 0);
            arr[0] = MFMA(a0, brf, arr[0], 0, 0, 0);
            arr[1] = MFMA(a1, brf, arr[1], 0, 0, 0);
            ahh[0] = MFMA(a0, bhf, ahh[0], 0, 0, 0);
            ahh[1] = MFMA(a1, bhf, ahh[1], 0, 0, 0);
        }

#pragma unroll
        for (int kt = 0; kt < 2; ++kt) {     // feat GEMM, K=64, weights in regs
            s16x8 a0 = *(const s16x8*)&xs[c * XS + kt * 32 + q * 8];
            s16x8 a1 = *(const s16x8*)&xs[(16 + c) * XS + kt * 32 + q * 8];
            az[0]  = MFMA(a0, wkr[kt][0], az[0], 0, 0, 0);
            az[1]  = MFMA(a1, wkr[kt][0], az[1], 0, 0, 0);
            arr[0] = MFMA(a0, wkr[kt][1], arr[0], 0, 0, 0);
            arr[1] = MFMA(a1, wkr[kt][1], arr[1], 0, 0, 0);
            axh[0] = MFMA(a0, wkr[kt][2], axh[0], 0, 0, 0);
            axh[1] = MFMA(a1, wkr[kt][2], axh[1], 0, 0, 0);
        }
        __syncthreads();   // S1: all hs/xs reads of this step done

        // ---- finish step t-1's dense output; broadcast prev_out ----
        if (t > 0) {
            int r = lane & 31;
            float s = dbv;
            const float (*wp)[BM] = wpart[(t - 1) & 1];
#pragma unroll
            for (int ww = 0; ww < 16; ++ww) s += wp[ww][r];
            if (w == 0 && lane < 32) outbuf[r * OS + (t - 1)] = s;
#pragma unroll
            for (int mt = 0; mt < 2; ++mt)
#pragma unroll
                for (int i = 0; i < 4; ++i)
                    prevreg[mt][i] = __shfl(s, mt * 16 + q * 4 + i, 64);
        }

        // ---- epilogue: gates, h update, dense partials ----
#pragma unroll
        for (int mt = 0; mt < 2; ++mt) {
            float sd[4];
#pragma unroll
            for (int i = 0; i < 4; ++i) {
                float pv = prevreg[mt][i];
                float zz = 1.0f / (1.0f + __expf(-(az[mt][i] + bz + pv * wk0z)));
                float rr = 1.0f / (1.0f + __expf(-(arr[mt][i] + brr + pv * wk0r)));
                float cd = tanhf(axh[mt][i] + bxh + pv * wk0h +
                                 rr * (ahh[mt][i] + bhh));
                float hn = zz * hreg[mt][i] + (1.0f - zz) * cd;
                hreg[mt][i] = hn;
                hs[(mt * 16 + q * 4 + i) * HS + colh] = f2bf(hn);
                sd[i] = hn * dwv;
            }
#pragma unroll
            for (int i = 0; i < 4; ++i) {
                float s = sd[i];
                s += __shfl_xor(s, 1, 64);
                s += __shfl_xor(s, 2, 64);
                s += __shfl_xor(s, 4, 64);
                s += __shfl_xor(s, 8, 64);
                if (c == 0) wpart[t & 1][w][mt * 16 + q * 4 + i] = s;
            }
        }

        // stage feat t+1 (xs reads for step t finished at S1)
        if (t + 1 < Tdim && tid < 512) {
            int r = tid >> 4, fi = tid & 15;
            float4 f = *(const float4*)&feat[((size_t)(b0 + r) * Tdim + (t + 1)) * Fdim + fi * 4];
            ushort4 p; p.x = f2bf(f.x); p.y = f2bf(f.y); p.z = f2bf(f.z); p.w = f2bf(f.w);
            *(ushort4*)&xs[r * XS + fi * 4] = p;
        }
        __syncthreads();   // S2: hs/wpart/xs writes visible
    }

    // final dense output for t=95
    {
        int r = lane & 31;
        float s = dbv;
        const float (*wp)[BM] = wpart[(Tdim - 1) & 1];
#pragma unroll
        for (int ww = 0; ww < 16; ++ww) s += wp[ww][r];
        if (w == 0 && lane < 32) outbuf[r * OS + (Tdim - 1)] = s;
    }
    __syncthreads();

    // coalesced dump: out[(b0+r)*96 + tt]
    for (int i = tid; i < BM * Tdim; i += 1024) {
        int r = i / Tdim, tt = i - r * Tdim;
        out[(size_t)b0 * Tdim + i] = outbuf[r * OS + tt];
    }
}

extern "C" void kernel_launch(void* const* d_in, const int* in_sizes, int n_in,
                              void* d_out, int out_size, void* d_ws, size_t ws_size,
                              hipStream_t stream) {
    const float* feat       = (const float*)d_in[0];
    const float* init_state = (const float*)d_in[1];
    const float* init_inp   = (const float*)d_in[2];
    const float* Wk         = (const float*)d_in[3];
    const float* Wr         = (const float*)d_in[4];
    const float* ib         = (const float*)d_in[5];
    const float* rb         = (const float*)d_in[6];
    const float* dw         = (const float*)d_in[7];
    const float* db         = (const float*)d_in[8];
    float* out              = (float*)d_out;

    unsigned short* sR = (unsigned short*)d_ws;                        // 384 KB
    unsigned short* sK = (unsigned short*)((char*)d_ws + 24576 * 16);  // 96 KB

    prep_swz<<<120, 256, 0, stream>>>(Wk, Wr, sK, sR);
    gru_mfma4<<<Bdim / BM, 1024, 0, stream>>>(
        feat, init_state, init_inp, sK, sR, Wk, ib, rb, dw, db, out);
}

// Round 6
// 1727.475 us; speedup vs baseline: 1.9120x; 1.9120x over previous
//
#include <hip/hip_runtime.h>

// GRU decoder, bf16 MFMA. R6: back to the only config that gives 128 arch
// VGPRs (512 thr, __launch_bounds__(512,2)); ALL weights streamed as
// swizzled B-fragments (no resident weight registers -> no spill/remat).
// Unified 10-K-tile loop: kt 0..7 = h @ Wr (A from hs), kt 8..9 = feat @ Wk
// rows 1..64 (A from xs). prev_out rank-1 term in fp32 epilogue.
// Block = BM=32 rows, T=96 steps. Wave w (0..7) owns cols [w*32,w*32+32)
// per gate. h carried fp32 in regs; bf16 copy in LDS for A-frags.

#define Bdim 8192
#define Tdim 96
#define Fdim 64
#define Hdim 256
#define BM   32
#define XS   72    // feat row stride (bf16): 64 + 8 pad
#define HS   264   // h row stride (bf16): 256 + 8 pad (multiple of 8)
#define OS   97    // outbuf row stride (floats)

typedef __attribute__((ext_vector_type(8))) short s16x8;
typedef __attribute__((ext_vector_type(4))) float f32x4;

#define MFMA __builtin_amdgcn_mfma_f32_16x16x32_bf16

__device__ __forceinline__ unsigned short f2bf(float f) {
    union { float f; unsigned u; } v; v.f = f;
    unsigned r = v.u + 0x7FFFu + ((v.u >> 16) & 1u);   // RNE
    return (unsigned short)(r >> 16);
}

// ---- one-time weight conversion + B-fragment swizzle ----
// frag f = ((w*10 + kt)*3 + g)*2 + n2, lane l: 8 bf16 at sW[f*512 + l*8].
// lane holds B[k][n], k = kt*32 + (l>>4)*8 + j, n = g*256 + w*32 + n2*16 + (l&15).
// kt 0..7: B row k = Wr[k]; kt 8..9: B row = Wk[1 + (kt-8)*32 + (l>>4)*8 + j].
// Per wave: 60 contiguous KB consumed per step.
__global__ void prep_swz(const float* __restrict__ Wk, const float* __restrict__ Wr,
                         unsigned short* __restrict__ sW) {
    int idx = blockIdx.x * blockDim.x + threadIdx.x;
    if (idx >= 480 * 64) return;
    int lane = idx & 63, f = idx >> 6;
    int n2 = f & 1;
    int g  = (f >> 1) % 3;
    int kt = (f / 6) % 10;
    int w  = f / 60;
    int q = lane >> 4, cc = lane & 15;
    int n = g * 256 + w * 32 + n2 * 16 + cc;
    unsigned short* d = sW + (size_t)idx * 8;
#pragma unroll
    for (int j = 0; j < 8; ++j) {
        float v;
        if (kt < 8) v = Wr[(size_t)(kt * 32 + q * 8 + j) * 768 + n];
        else        v = Wk[(size_t)(1 + (kt - 8) * 32 + q * 8 + j) * 768 + n];
        d[j] = f2bf(v);
    }
}

__launch_bounds__(512, 2)
__global__ void gru_mfma5(
    const float* __restrict__ feat,       // [B,T,F]
    const float* __restrict__ init_state, // [B,H]
    const float* __restrict__ init_inp,   // [B,1]
    const unsigned short* __restrict__ sW,
    const float* __restrict__ Wk,         // row 0 (prev_out rank-1 term)
    const float* __restrict__ ib, const float* __restrict__ rb,
    const float* __restrict__ dw, const float* __restrict__ db,
    float* __restrict__ out)              // [B,T,1]
{
    __shared__ __align__(16) unsigned short xs[BM * XS];  // feat tile, bf16
    __shared__ __align__(16) unsigned short hs[BM * HS];  // h state, bf16
    __shared__ float wpart[2][8][BM];                     // dbl-buffered by t&1
    __shared__ float outbuf[BM * OS];

    const int tid  = threadIdx.x;
    const int lane = tid & 63;
    const int w    = tid >> 6;     // wave 0..7: cols [w*32, w*32+32) per gate
    const int q    = lane >> 4;
    const int c    = lane & 15;
    const int b0   = blockIdx.x * BM;

    // per-lane epilogue constants, col = g*256 + w*32 + n2*16 + c
    float bz[2], brr[2], bxh[2], bhh[2], wk0z[2], wk0r[2], wk0h[2], dwv[2];
#pragma unroll
    for (int n2 = 0; n2 < 2; ++n2) {
        int col = w * 32 + n2 * 16 + c;
        bz[n2]   = ib[col]       + rb[col];
        brr[n2]  = ib[256 + col] + rb[256 + col];
        bxh[n2]  = ib[512 + col];
        bhh[n2]  = rb[512 + col];
        wk0z[n2] = Wk[col];
        wk0r[n2] = Wk[256 + col];
        wk0h[n2] = Wk[512 + col];
        dwv[n2]  = dw[col];
    }
    const float dbv = db[0];

    // init h: fp32 in regs + bf16 in LDS
    float hreg[2][2][4];   // [mt][n2][i]
    float prevreg[2][4];   // [mt][i]
#pragma unroll
    for (int mt = 0; mt < 2; ++mt)
#pragma unroll
        for (int i = 0; i < 4; ++i) {
            int row = mt * 16 + q * 4 + i;
            prevreg[mt][i] = init_inp[b0 + row];
#pragma unroll
            for (int n2 = 0; n2 < 2; ++n2) {
                int col = w * 32 + n2 * 16 + c;
                float v = init_state[(size_t)(b0 + row) * Hdim + col];
                hreg[mt][n2][i] = v;
                hs[row * HS + col] = f2bf(v);
            }
        }

    // stage feat t=0 (512 threads: 32 rows x 16 float4)
    {
        int r = tid >> 4, fi = tid & 15;
        float4 f = *(const float4*)&feat[((size_t)(b0 + r) * Tdim + 0) * Fdim + fi * 4];
        ushort4 p; p.x = f2bf(f.x); p.y = f2bf(f.y); p.z = f2bf(f.z); p.w = f2bf(f.w);
        *(ushort4*)&xs[r * XS + fi * 4] = p;
    }

    const unsigned short* wp0 = sW + (size_t)(w * 60) * 512 + lane * 8;

    __syncthreads();

    for (int t = 0; t < Tdim; ++t) {
        // ---- unified K-loop: kt 0..7 from hs (Wr), kt 8..9 from xs (Wk) ----
        f32x4 az[2][2], arr[2][2], axh[2][2], ahh[2][2];
#pragma unroll
        for (int mt = 0; mt < 2; ++mt)
#pragma unroll
            for (int n2 = 0; n2 < 2; ++n2) {
                az[mt][n2] = (f32x4)0.0f; arr[mt][n2] = (f32x4)0.0f;
                axh[mt][n2] = (f32x4)0.0f; ahh[mt][n2] = (f32x4)0.0f;
            }

#pragma unroll
        for (int kt = 0; kt < 10; ++kt) {
            const unsigned short* fp = wp0 + (size_t)(kt * 6) * 512;
            s16x8 b00 = *(const s16x8*)(fp + 0 * 512);
            s16x8 b01 = *(const s16x8*)(fp + 1 * 512);
            s16x8 b10 = *(const s16x8*)(fp + 2 * 512);
            s16x8 b11 = *(const s16x8*)(fp + 3 * 512);
            s16x8 b20 = *(const s16x8*)(fp + 4 * 512);
            s16x8 b21 = *(const s16x8*)(fp + 5 * 512);
            s16x8 a0, a1;
            if (kt < 8) {
                a0 = *(const s16x8*)&hs[c * HS + kt * 32 + q * 8];
                a1 = *(const s16x8*)&hs[(16 + c) * HS + kt * 32 + q * 8];
            } else {
                a0 = *(const s16x8*)&xs[c * XS + (kt - 8) * 32 + q * 8];
                a1 = *(const s16x8*)&xs[(16 + c) * XS + (kt - 8) * 32 + q * 8];
            }
            az[0][0]  = MFMA(a0, b00, az[0][0], 0, 0, 0);
            az[1][0]  = MFMA(a1, b00, az[1][0], 0, 0, 0);
            az[0][1]  = MFMA(a0, b01, az[0][1], 0, 0, 0);
            az[1][1]  = MFMA(a1, b01, az[1][1], 0, 0, 0);
            arr[0][0] = MFMA(a0, b10, arr[0][0], 0, 0, 0);
            arr[1][0] = MFMA(a1, b10, arr[1][0], 0, 0, 0);
            arr[0][1] = MFMA(a0, b11, arr[0][1], 0, 0, 0);
            arr[1][1] = MFMA(a1, b11, arr[1][1], 0, 0, 0);
            if (kt < 8) {   // hh terms
                ahh[0][0] = MFMA(a0, b20, ahh[0][0], 0, 0, 0);
                ahh[1][0] = MFMA(a1, b20, ahh[1][0], 0, 0, 0);
                ahh[0][1] = MFMA(a0, b21, ahh[0][1], 0, 0, 0);
                ahh[1][1] = MFMA(a1, b21, ahh[1][1], 0, 0, 0);
            } else {        // xh terms
                axh[0][0] = MFMA(a0, b20, axh[0][0], 0, 0, 0);
                axh[1][0] = MFMA(a1, b20, axh[1][0], 0, 0, 0);
                axh[0][1] = MFMA(a0, b21, axh[0][1], 0, 0, 0);
                axh[1][1] = MFMA(a1, b21, axh[1][1], 0, 0, 0);
            }
        }
        __syncthreads();   // S1: all hs/xs reads of this step done

        // ---- finish step t-1's dense output; broadcast prev_out ----
        if (t > 0) {
            int r = lane & 31;
            float s = dbv;
            const float (*wp)[BM] = wpart[(t - 1) & 1];
#pragma unroll
            for (int ww = 0; ww < 8; ++ww) s += wp[ww][r];
            if (w == 0 && lane < 32) outbuf[r * OS + (t - 1)] = s;
#pragma unroll
            for (int mt = 0; mt < 2; ++mt)
#pragma unroll
                for (int i = 0; i < 4; ++i)
                    prevreg[mt][i] = __shfl(s, mt * 16 + q * 4 + i, 64);
        }

        // ---- epilogue: gates, h update, dense partials ----
        float sd[2][4];
#pragma unroll
        for (int mt = 0; mt < 2; ++mt)
#pragma unroll
            for (int i = 0; i < 4; ++i) sd[mt][i] = 0.0f;

#pragma unroll
        for (int mt = 0; mt < 2; ++mt)
#pragma unroll
            for (int n2 = 0; n2 < 2; ++n2)
#pragma unroll
                for (int i = 0; i < 4; ++i) {
                    float pv = prevreg[mt][i];
                    float zz = 1.0f / (1.0f + __expf(-(az[mt][n2][i] + bz[n2] + pv * wk0z[n2])));
                    float rr = 1.0f / (1.0f + __expf(-(arr[mt][n2][i] + brr[n2] + pv * wk0r[n2])));
                    float cd = tanhf(axh[mt][n2][i] + bxh[n2] + pv * wk0h[n2] +
                                     rr * (ahh[mt][n2][i] + bhh[n2]));
                    float hn = zz * hreg[mt][n2][i] + (1.0f - zz) * cd;
                    hreg[mt][n2][i] = hn;
                    hs[(mt * 16 + q * 4 + i) * HS + w * 32 + n2 * 16 + c] = f2bf(hn);
                    sd[mt][i] += hn * dwv[n2];
                }

#pragma unroll
        for (int mt = 0; mt < 2; ++mt)
#pragma unroll
            for (int i = 0; i < 4; ++i) {
                float s = sd[mt][i];
                s += __shfl_xor(s, 1, 64);
                s += __shfl_xor(s, 2, 64);
                s += __shfl_xor(s, 4, 64);
                s += __shfl_xor(s, 8, 64);
                if (c == 0) wpart[t & 1][w][mt * 16 + q * 4 + i] = s;
            }

        // stage feat t+1 (xs reads for step t finished at S1)
        if (t + 1 < Tdim) {
            int r = tid >> 4, fi = tid & 15;
            float4 f = *(const float4*)&feat[((size_t)(b0 + r) * Tdim + (t + 1)) * Fdim + fi * 4];
            ushort4 p; p.x = f2bf(f.x); p.y = f2bf(f.y); p.z = f2bf(f.z); p.w = f2bf(f.w);
            *(ushort4*)&xs[r * XS + fi * 4] = p;
        }
        __syncthreads();   // S2: hs/wpart/xs writes visible
    }

    // final dense output for t=95
    {
        int r = lane & 31;
        float s = dbv;
        const float (*wp)[BM] = wpart[(Tdim - 1) & 1];
#pragma unroll
        for (int ww = 0; ww < 8; ++ww) s += wp[ww][r];
        if (w == 0 && lane < 32) outbuf[r * OS + (Tdim - 1)] = s;
    }
    __syncthreads();

    // coalesced dump: out[(b0+r)*96 + tt]
    for (int i = tid; i < BM * Tdim; i += 512) {
        int r = i / Tdim, tt = i - r * Tdim;
        out[(size_t)b0 * Tdim + i] = outbuf[r * OS + tt];
    }
}

extern "C" void kernel_launch(void* const* d_in, const int* in_sizes, int n_in,
                              void* d_out, int out_size, void* d_ws, size_t ws_size,
                              hipStream_t stream) {
    const float* feat       = (const float*)d_in[0];
    const float* init_state = (const float*)d_in[1];
    const float* init_inp   = (const float*)d_in[2];
    const float* Wk         = (const float*)d_in[3];
    const float* Wr         = (const float*)d_in[4];
    const float* ib         = (const float*)d_in[5];
    const float* rb         = (const float*)d_in[6];
    const float* dw         = (const float*)d_in[7];
    const float* db         = (const float*)d_in[8];
    float* out              = (float*)d_out;

    unsigned short* sW = (unsigned short*)d_ws;   // 480 frags * 1 KB = 480 KB

    prep_swz<<<120, 256, 0, stream>>>(Wk, Wr, sW);
    gru_mfma5<<<Bdim / BM, 512, 0, stream>>>(
        feat, init_state, init_inp, sW, Wk, ib, rb, dw, db, out);
}

// Round 7
// 1726.072 us; speedup vs baseline: 1.9136x; 1.0008x over previous
//
#include <hip/hip_runtime.h>

// GRU decoder, bf16 MFMA. R7: kill the last spills.
// Grid = 256 blocks = 1 block/CU always, so launch_bounds(512,1) (256-reg cap)
// costs no occupancy and removes all scratch (R6 @128 regs still spilled:
// 75 MB scratch writes -> L2 thrash -> 3.7 GB weight-stream misses).
// Freed registers fund a distance-2 software pipeline on the weight
// fragment stream (3 x 6 frags in flight) to hide ~200cyc L2 latency at
// 2 waves/SIMD.
// Structure unchanged from R6: BM=32 rows/block, T=96 steps, unified
// 10-K-tile loop (kt 0..7 = h@Wr from hs, kt 8..9 = feat@Wk from xs),
// prev_out rank-1 term in fp32 epilogue, h fp32 in regs + bf16 in LDS.

#define Bdim 8192
#define Tdim 96
#define Fdim 64
#define Hdim 256
#define BM   32
#define XS   72    // feat row stride (bf16): 64 + 8 pad
#define HS   264   // h row stride (bf16): 256 + 8 pad
#define OS   97    // outbuf row stride (floats)

typedef __attribute__((ext_vector_type(8))) short s16x8;
typedef __attribute__((ext_vector_type(4))) float f32x4;

#define MFMA __builtin_amdgcn_mfma_f32_16x16x32_bf16

__device__ __forceinline__ unsigned short f2bf(float f) {
    union { float f; unsigned u; } v; v.f = f;
    unsigned r = v.u + 0x7FFFu + ((v.u >> 16) & 1u);   // RNE
    return (unsigned short)(r >> 16);
}

// ---- one-time weight conversion + B-fragment swizzle ----
// frag f = ((w*10 + kt)*3 + g)*2 + n2, lane l: 8 bf16 at sW[f*512 + l*8].
// lane holds B[k][n], k = kt*32 + (l>>4)*8 + j, n = g*256 + w*32 + n2*16 + (l&15).
// kt 0..7: B row k = Wr[k]; kt 8..9: B row = Wk[1 + (kt-8)*32 + (l>>4)*8 + j].
__global__ void prep_swz(const float* __restrict__ Wk, const float* __restrict__ Wr,
                         unsigned short* __restrict__ sW) {
    int idx = blockIdx.x * blockDim.x + threadIdx.x;
    if (idx >= 480 * 64) return;
    int lane = idx & 63, f = idx >> 6;
    int n2 = f & 1;
    int g  = (f >> 1) % 3;
    int kt = (f / 6) % 10;
    int w  = f / 60;
    int q = lane >> 4, cc = lane & 15;
    int n = g * 256 + w * 32 + n2 * 16 + cc;
    unsigned short* d = sW + (size_t)idx * 8;
#pragma unroll
    for (int j = 0; j < 8; ++j) {
        float v;
        if (kt < 8) v = Wr[(size_t)(kt * 32 + q * 8 + j) * 768 + n];
        else        v = Wk[(size_t)(1 + (kt - 8) * 32 + q * 8 + j) * 768 + n];
        d[j] = f2bf(v);
    }
}

__launch_bounds__(512, 1)
__global__ void gru_mfma6(
    const float* __restrict__ feat,       // [B,T,F]
    const float* __restrict__ init_state, // [B,H]
    const float* __restrict__ init_inp,   // [B,1]
    const unsigned short* __restrict__ sW,
    const float* __restrict__ Wk,         // row 0 (prev_out rank-1 term)
    const float* __restrict__ ib, const float* __restrict__ rb,
    const float* __restrict__ dw, const float* __restrict__ db,
    float* __restrict__ out)              // [B,T,1]
{
    __shared__ __align__(16) unsigned short xs[BM * XS];  // feat tile, bf16
    __shared__ __align__(16) unsigned short hs[BM * HS];  // h state, bf16
    __shared__ float wpart[2][8][BM];                     // dbl-buffered by t&1
    __shared__ float outbuf[BM * OS];

    const int tid  = threadIdx.x;
    const int lane = tid & 63;
    const int w    = tid >> 6;     // wave 0..7: cols [w*32, w*32+32) per gate
    const int q    = lane >> 4;
    const int c    = lane & 15;
    const int b0   = blockIdx.x * BM;

    // per-lane epilogue constants, col = g*256 + w*32 + n2*16 + c
    float bz[2], brr[2], bxh[2], bhh[2], wk0z[2], wk0r[2], wk0h[2], dwv[2];
#pragma unroll
    for (int n2 = 0; n2 < 2; ++n2) {
        int col = w * 32 + n2 * 16 + c;
        bz[n2]   = ib[col]       + rb[col];
        brr[n2]  = ib[256 + col] + rb[256 + col];
        bxh[n2]  = ib[512 + col];
        bhh[n2]  = rb[512 + col];
        wk0z[n2] = Wk[col];
        wk0r[n2] = Wk[256 + col];
        wk0h[n2] = Wk[512 + col];
        dwv[n2]  = dw[col];
    }
    const float dbv = db[0];

    // init h: fp32 in regs + bf16 in LDS
    float hreg[2][2][4];   // [mt][n2][i]
    float prevreg[2][4];   // [mt][i]
#pragma unroll
    for (int mt = 0; mt < 2; ++mt)
#pragma unroll
        for (int i = 0; i < 4; ++i) {
            int row = mt * 16 + q * 4 + i;
            prevreg[mt][i] = init_inp[b0 + row];
#pragma unroll
            for (int n2 = 0; n2 < 2; ++n2) {
                int col = w * 32 + n2 * 16 + c;
                float v = init_state[(size_t)(b0 + row) * Hdim + col];
                hreg[mt][n2][i] = v;
                hs[row * HS + col] = f2bf(v);
            }
        }

    // stage feat t=0 (512 threads: 32 rows x 16 float4)
    {
        int r = tid >> 4, fi = tid & 15;
        float4 f = *(const float4*)&feat[((size_t)(b0 + r) * Tdim + 0) * Fdim + fi * 4];
        ushort4 p; p.x = f2bf(f.x); p.y = f2bf(f.y); p.z = f2bf(f.z); p.w = f2bf(f.w);
        *(ushort4*)&xs[r * XS + fi * 4] = p;
    }

    const unsigned short* wp0 = sW + (size_t)(w * 60) * 512 + lane * 8;

    __syncthreads();

    for (int t = 0; t < Tdim; ++t) {
        // ---- unified K-loop, distance-2 prefetched weight fragments ----
        f32x4 az[2][2], arr[2][2], axh[2][2], ahh[2][2];
#pragma unroll
        for (int mt = 0; mt < 2; ++mt)
#pragma unroll
            for (int n2 = 0; n2 < 2; ++n2) {
                az[mt][n2] = (f32x4)0.0f; arr[mt][n2] = (f32x4)0.0f;
                axh[mt][n2] = (f32x4)0.0f; ahh[mt][n2] = (f32x4)0.0f;
            }

        s16x8 bf[3][6];
#pragma unroll
        for (int p = 0; p < 2; ++p) {
            const unsigned short* fp = wp0 + (size_t)(p * 6) * 512;
#pragma unroll
            for (int u = 0; u < 6; ++u) bf[p][u] = *(const s16x8*)(fp + u * 512);
        }

#pragma unroll
        for (int kt = 0; kt < 10; ++kt) {
            if (kt + 2 < 10) {
                const unsigned short* fp = wp0 + (size_t)((kt + 2) * 6) * 512;
#pragma unroll
                for (int u = 0; u < 6; ++u)
                    bf[(kt + 2) % 3][u] = *(const s16x8*)(fp + u * 512);
            }
            const s16x8* b = bf[kt % 3];
            s16x8 a0, a1;
            if (kt < 8) {
                a0 = *(const s16x8*)&hs[c * HS + kt * 32 + q * 8];
                a1 = *(const s16x8*)&hs[(16 + c) * HS + kt * 32 + q * 8];
            } else {
                a0 = *(const s16x8*)&xs[c * XS + (kt - 8) * 32 + q * 8];
                a1 = *(const s16x8*)&xs[(16 + c) * XS + (kt - 8) * 32 + q * 8];
            }
            az[0][0]  = MFMA(a0, b[0], az[0][0], 0, 0, 0);
            az[1][0]  = MFMA(a1, b[0], az[1][0], 0, 0, 0);
            az[0][1]  = MFMA(a0, b[1], az[0][1], 0, 0, 0);
            az[1][1]  = MFMA(a1, b[1], az[1][1], 0, 0, 0);
            arr[0][0] = MFMA(a0, b[2], arr[0][0], 0, 0, 0);
            arr[1][0] = MFMA(a1, b[2], arr[1][0], 0, 0, 0);
            arr[0][1] = MFMA(a0, b[3], arr[0][1], 0, 0, 0);
            arr[1][1] = MFMA(a1, b[3], arr[1][1], 0, 0, 0);
            if (kt < 8) {   // hh terms
                ahh[0][0] = MFMA(a0, b[4], ahh[0][0], 0, 0, 0);
                ahh[1][0] = MFMA(a1, b[4], ahh[1][0], 0, 0, 0);
                ahh[0][1] = MFMA(a0, b[5], ahh[0][1], 0, 0, 0);
                ahh[1][1] = MFMA(a1, b[5], ahh[1][1], 0, 0, 0);
            } else {        // xh terms
                axh[0][0] = MFMA(a0, b[4], axh[0][0], 0, 0, 0);
                axh[1][0] = MFMA(a1, b[4], axh[1][0], 0, 0, 0);
                axh[0][1] = MFMA(a0, b[5], axh[0][1], 0, 0, 0);
                axh[1][1] = MFMA(a1, b[5], axh[1][1], 0, 0, 0);
            }
        }
        __syncthreads();   // S1: all hs/xs reads of this step done

        // ---- finish step t-1's dense output; broadcast prev_out ----
        if (t > 0) {
            int r = lane & 31;
            float s = dbv;
            const float (*wp)[BM] = wpart[(t - 1) & 1];
#pragma unroll
            for (int ww = 0; ww < 8; ++ww) s += wp[ww][r];
            if (w == 0 && lane < 32) outbuf[r * OS + (t - 1)] = s;
#pragma unroll
            for (int mt = 0; mt < 2; ++mt)
#pragma unroll
                for (int i = 0; i < 4; ++i)
                    prevreg[mt][i] = __shfl(s, mt * 16 + q * 4 + i, 64);
        }

        // ---- epilogue: gates, h update, dense partials ----
        float sd[2][4];
#pragma unroll
        for (int mt = 0; mt < 2; ++mt)
#pragma unroll
            for (int i = 0; i < 4; ++i) sd[mt][i] = 0.0f;

#pragma unroll
        for (int mt = 0; mt < 2; ++mt)
#pragma unroll
            for (int n2 = 0; n2 < 2; ++n2)
#pragma unroll
                for (int i = 0; i < 4; ++i) {
                    float pv = prevreg[mt][i];
                    float zz = 1.0f / (1.0f + __expf(-(az[mt][n2][i] + bz[n2] + pv * wk0z[n2])));
                    float rr = 1.0f / (1.0f + __expf(-(arr[mt][n2][i] + brr[n2] + pv * wk0r[n2])));
                    float cd = tanhf(axh[mt][n2][i] + bxh[n2] + pv * wk0h[n2] +
                                     rr * (ahh[mt][n2][i] + bhh[n2]));
                    float hn = zz * hreg[mt][n2][i] + (1.0f - zz) * cd;
                    hreg[mt][n2][i] = hn;
                    hs[(mt * 16 + q * 4 + i) * HS + w * 32 + n2 * 16 + c] = f2bf(hn);
                    sd[mt][i] += hn * dwv[n2];
                }

#pragma unroll
        for (int mt = 0; mt < 2; ++mt)
#pragma unroll
            for (int i = 0; i < 4; ++i) {
                float s = sd[mt][i];
                s += __shfl_xor(s, 1, 64);
                s += __shfl_xor(s, 2, 64);
                s += __shfl_xor(s, 4, 64);
                s += __shfl_xor(s, 8, 64);
                if (c == 0) wpart[t & 1][w][mt * 16 + q * 4 + i] = s;
            }

        // stage feat t+1 (xs reads for step t finished at S1)
        if (t + 1 < Tdim) {
            int r = tid >> 4, fi = tid & 15;
            float4 f = *(const float4*)&feat[((size_t)(b0 + r) * Tdim + (t + 1)) * Fdim + fi * 4];
            ushort4 p; p.x = f2bf(f.x); p.y = f2bf(f.y); p.z = f2bf(f.z); p.w = f2bf(f.w);
            *(ushort4*)&xs[r * XS + fi * 4] = p;
        }
        __syncthreads();   // S2: hs/wpart/xs writes visible
    }

    // final dense output for t=95
    {
        int r = lane & 31;
        float s = dbv;
        const float (*wp)[BM] = wpart[(Tdim - 1) & 1];
#pragma unroll
        for (int ww = 0; ww < 8; ++ww) s += wp[ww][r];
        if (w == 0 && lane < 32) outbuf[r * OS + (Tdim - 1)] = s;
    }
    __syncthreads();

    // coalesced dump: out[(b0+r)*96 + tt]
    for (int i = tid; i < BM * Tdim; i += 512) {
        int r = i / Tdim, tt = i - r * Tdim;
        out[(size_t)b0 * Tdim + i] = outbuf[r * OS + tt];
    }
}

extern "C" void kernel_launch(void* const* d_in, const int* in_sizes, int n_in,
                              void* d_out, int out_size, void* d_ws, size_t ws_size,
                              hipStream_t stream) {
    const float* feat       = (const float*)d_in[0];
    const float* init_state = (const float*)d_in[1];
    const float* init_inp   = (const float*)d_in[2];
    const float* Wk         = (const float*)d_in[3];
    const float* Wr         = (const float*)d_in[4];
    const float* ib         = (const float*)d_in[5];
    const float* rb         = (const float*)d_in[6];
    const float* dw         = (const float*)d_in[7];
    const float* db         = (const float*)d_in[8];
    float* out              = (float*)d_out;

    unsigned short* sW = (unsigned short*)d_ws;   // 480 frags * 1 KB = 480 KB

    prep_swz<<<120, 256, 0, stream>>>(Wk, Wr, sW);
    gru_mfma6<<<Bdim / BM, 512, 0, stream>>>(
        feat, init_state, init_inp, sW, Wk, ib, rb, dw, db, out);
}